// Round 8
// baseline (32.878 us; speedup 1.0000x reference)
//
#include <hip/hip_runtime.h>
#include <math.h>

#define B_TOTAL 16384
#define NQ 512
#define NUM 3

// One wave per batch. NUM=3 greedy NMS == three masked argmaxes:
//   #1 = argmax conf; #2 = argmax among passers vs p1; #3 = passers vs p1&p2.
// Lane l holds conf[8l..8l+7] as monotone u32 keys and pos rows 8l..8l+7 in
// registers (coalesced single pass). Argmax = local value+index tree packed
// into u64 (key<<32 | 511-n) + 6-step butterfly (stable min-index tie-break).
// Forced <=64 VGPR (launch_bounds 8 waves/EU) for 8 waves/SIMD latency hiding.
__global__ __launch_bounds__(256, 8) void greedy_nms_kernel(
    const float* __restrict__ conf,   // [B, NQ]
    const float* __restrict__ pos,    // [B, NQ, 3]
    float* __restrict__ out)          // [B, NUM, 3]
{
    const int lane = threadIdx.x & 63;
    const int b = (blockIdx.x << 2) | (threadIdx.x >> 6);   // 4 waves/block

    const float* cb = conf + (size_t)b * NQ;
    const float* pb = pos  + (size_t)b * NQ * 3;

    // ---- issue all global loads up front (independent, coalesced) ----
    const float4* cb4 = reinterpret_cast<const float4*>(cb);
    float4 c0 = cb4[lane * 2 + 0];
    float4 c1 = cb4[lane * 2 + 1];
    const float4* pb4 = reinterpret_cast<const float4*>(pb);
    float4 q0 = pb4[lane * 6 + 0];
    float4 q1 = pb4[lane * 6 + 1];
    float4 q2 = pb4[lane * 6 + 2];
    float4 q3 = pb4[lane * 6 + 3];
    float4 q4 = pb4[lane * 6 + 4];
    float4 q5 = pb4[lane * 6 + 5];

    // monotone float->u32 keys (no NaNs in input); key 0 == consumed/failed
    unsigned k[8];
    {
        float f[8] = {c0.x, c0.y, c0.z, c0.w, c1.x, c1.y, c1.z, c1.w};
        #pragma unroll
        for (int s = 0; s < 8; ++s) {
            int bi = __float_as_int(f[s]);
            k[s] = (unsigned)bi ^ ((unsigned)(bi >> 31) | 0x80000000u);
        }
    }

    // pos rows: row j of this lane = element 8*lane + j
    float rx[8], ry[8], rz[8];
    rx[0] = q0.x; ry[0] = q0.y; rz[0] = q0.z;
    rx[1] = q0.w; ry[1] = q1.x; rz[1] = q1.y;
    rx[2] = q1.z; ry[2] = q1.w; rz[2] = q2.x;
    rx[3] = q2.y; ry[3] = q2.z; rz[3] = q2.w;
    rx[4] = q3.x; ry[4] = q3.y; rz[4] = q3.z;
    rx[5] = q3.w; ry[5] = q4.x; rz[5] = q4.y;
    rx[6] = q4.z; ry[6] = q4.w; rz[6] = q5.x;
    rx[7] = q5.y; ry[7] = q5.z; rz[7] = q5.w;

    // exact argmax over current keys -> packed u64 (hi=key, lo=511-n).
    // tie -> larger lo -> smaller n, identical to stable argsort(-conf).
    auto argmax64 = [&]() -> unsigned long long {
        bool s01 = k[1] > k[0];
        unsigned m01 = s01 ? k[1] : k[0]; int i01 = s01 ? 1 : 0;
        bool s23 = k[3] > k[2];
        unsigned m23 = s23 ? k[3] : k[2]; int i23 = s23 ? 3 : 2;
        bool s45 = k[5] > k[4];
        unsigned m45 = s45 ? k[5] : k[4]; int i45 = s45 ? 5 : 4;
        bool s67 = k[7] > k[6];
        unsigned m67 = s67 ? k[7] : k[6]; int i67 = s67 ? 7 : 6;
        if (m23 > m01) { m01 = m23; i01 = i23; }
        if (m67 > m45) { m45 = m67; i45 = i67; }
        if (m45 > m01) { m01 = m45; i01 = i45; }
        unsigned long long key =
            ((unsigned long long)m01 << 32) |
            (unsigned)(NQ - 1 - ((lane << 3) + i01));
        #pragma unroll
        for (int off = 1; off < 64; off <<= 1) {
            unsigned long long o = __shfl_xor(key, off);
            if (o > key) key = o;
        }
        return key;
    };

    // broadcast row w's xyz to all lanes (w wave-uniform)
    auto get_row = [&](int w, float& x, float& y, float& z) {
        const int ow = w >> 3, sl = w & 7;
        float tx = rx[0], ty = ry[0], tz = rz[0];
        #pragma unroll
        for (int s = 1; s < 8; ++s)
            if (sl == s) { tx = rx[s]; ty = ry[s]; tz = rz[s]; }
        x = __shfl(tx, ow); y = __shfl(ty, ow); z = __shfl(tz, ow);
    };

    const float TH  = 0.78539816339744830961f; // pi/4 (f32 == jnp thresh)
    const float CLO = 0.70710478f;             // cos(pi/4) - ~2e-6
    const float CHI = 0.70710878f;             // cos(pi/4) + ~2e-6

    // zero keys of items failing the angle test vs (px,py,pz)
    auto mask_keys = [&](float px, float py, float pz) {
        #pragma unroll
        for (int s = 0; s < 8; ++s) {
            float d = fabsf(rx[s] * px + ry[s] * py + rz[s] * pz);
            bool pass;
            if (d <= CLO)      pass = true;   // clearly >= pi/4
            else if (d >= CHI) pass = false;  // clearly <  pi/4
            else               pass = (acosf(fminf(d, 1.f)) >= TH); // exact
            if (!pass) k[s] = 0u;
        }
    };

    // ---- #1: global argmax ----
    unsigned long long K1 = argmax64();
    const int w1 = NQ - 1 - (int)(K1 & 0x1ffu);
    float p1x, p1y, p1z;
    get_row(w1, p1x, p1y, p1z);
    {   // consume w1
        const int osl = ((w1 >> 3) == lane) ? (w1 & 7) : 8;
        #pragma unroll
        for (int s = 0; s < 8; ++s)
            if (osl == s) k[s] = 0u;
    }

    // ---- #2: argmax among items passing vs p1 ----
    mask_keys(p1x, p1y, p1z);
    unsigned long long K2 = argmax64();

    float o2x, o2y, o2z, o3x, o3y, o3z;
    if ((unsigned)(K2 >> 32) != 0u) {         // wave-uniform
        const int w2 = NQ - 1 - (int)(K2 & 0x1ffu);
        get_row(w2, o2x, o2y, o2z);
        // ---- #3: additionally pass vs p2 (w2 self-fails: |dot|=1) ----
        mask_keys(o2x, o2y, o2z);
        unsigned long long K3 = argmax64();
        if ((unsigned)(K3 >> 32) != 0u) {
            const int w3 = NQ - 1 - (int)(K3 & 0x1ffu);
            get_row(w3, o3x, o3y, o3z);
        } else {
            get_row(0, o3x, o3y, o3z);        // fallback = pos[0]
        }
    } else {
        get_row(0, o2x, o2y, o2z);            // fallback = pos[0]
        o3x = o2x; o3y = o2y; o3z = o2z;
    }

    if (lane == 0) {
        float* ob = out + (size_t)b * 9;
        ob[0] = p1x; ob[1] = p1y; ob[2] = p1z;
        ob[3] = o2x; ob[4] = o2y; ob[5] = o2z;
        ob[6] = o3x; ob[7] = o3y; ob[8] = o3z;
    }
}

extern "C" void kernel_launch(void* const* d_in, const int* in_sizes, int n_in,
                              void* d_out, int out_size, void* d_ws, size_t ws_size,
                              hipStream_t stream) {
    const float* pred_logits = (const float*)d_in[0]; // [B, NQ, 1]
    const float* pred_pos    = (const float*)d_in[1]; // [B, NQ, 3]
    float* out = (float*)d_out;                       // [B, NUM, 3]

    const int grid = B_TOTAL / 4;                     // 4 waves/block
    greedy_nms_kernel<<<grid, 256, 0, stream>>>(pred_logits, pred_pos, out);
}

// Round 9
// 32.249 us; speedup vs baseline: 1.0195x; 1.0195x over previous
//
#include <hip/hip_runtime.h>
#include <math.h>

#define B_TOTAL 16384
#define NQ 512
#define NUM 3
#define TOPK 16

// One wave per batch.
// Phase 1: extract top-16 conf indices in order via 16x argmax-consume
//          (R6-proven 32-bit butterfly + ballot/ffs min-index tie-break).
// Phase 2: gather those 16 pos rows only (lane i holds rank-i row).
// Phase 3: greedy over ranks via ballots: #1 = rank0; #2 = first rank in
//          1..15 passing vs p1; #3 = first rank > i2 passing vs p1 AND p2.
// Fallback (wave-uniform, ~1e-4 of batches): full R6 masked-argmax scan.
__global__ __launch_bounds__(256) void greedy_nms_kernel(
    const float* __restrict__ conf,   // [B, NQ]
    const float* __restrict__ pos,    // [B, NQ, 3]
    float* __restrict__ out)          // [B, NUM, 3]
{
    const int lane = threadIdx.x & 63;
    const int b = (blockIdx.x << 2) | (threadIdx.x >> 6);   // 4 waves/block

    const float* cb = conf + (size_t)b * NQ;
    const float* pb = pos  + (size_t)b * NQ * 3;

    const float4* cb4 = reinterpret_cast<const float4*>(cb);
    float4 c0 = cb4[lane * 2 + 0];
    float4 c1 = cb4[lane * 2 + 1];

    // monotone float->u32 keys; key 0 unreachable for non-NaN inputs
    unsigned k[8];
    {
        float f[8] = {c0.x, c0.y, c0.z, c0.w, c1.x, c1.y, c1.z, c1.w};
        #pragma unroll
        for (int s = 0; s < 8; ++s) {
            int bi = __float_as_int(f[s]);
            k[s] = (unsigned)bi ^ ((unsigned)(bi >> 31) | 0x80000000u);
        }
    }

    // ---- phase 1: top-16 extraction (exact order, exact ties) ----
    int myw = 0;   // lane i<16 ends with the rank-i element index
    #pragma unroll
    for (int i = 0; i < TOPK; ++i) {
        unsigned m = k[0];
        #pragma unroll
        for (int s = 1; s < 8; ++s) m = k[s] > m ? k[s] : m;
        unsigned gm = m;
        #pragma unroll
        for (int off = 1; off < 64; off <<= 1) {
            unsigned o = __shfl_xor(gm, off);
            gm = o > gm ? o : gm;
        }
        int sl = 8;
        #pragma unroll
        for (int s = 7; s >= 0; --s)
            if (k[s] == gm) sl = s;                 // first local slot == max
        unsigned long long ball = __ballot(sl < 8);
        int owner = __ffsll(ball) - 1;              // min lane -> min index
        int osl = __shfl(sl, owner);
        if (lane == i) myw = owner * 8 + osl;
        const int cs = (owner == lane) ? osl : 8;   // consume winner
        #pragma unroll
        for (int s = 0; s < 8; ++s)
            if (cs == s) k[s] = 0u;
    }

    // ---- phase 2: gather the 16 candidate rows (lanes >=16 fetch row 0) ----
    float cx = pb[myw * 3 + 0];
    float cy = pb[myw * 3 + 1];
    float cz = pb[myw * 3 + 2];

    const float TH  = 0.78539816339744830961f; // pi/4 (f32 == jnp thresh)
    const float CLO = 0.70710478f;             // cos(pi/4) - ~2e-6
    const float CHI = 0.70710878f;             // cos(pi/4) + ~2e-6

    auto my_pass = [&](float px, float py, float pz) -> bool {
        float d = fabsf(cx * px + cy * py + cz * pz);
        if (d <= CLO) return true;                  // clearly >= pi/4
        if (d >= CHI) return false;                 // clearly <  pi/4
        return acosf(fminf(d, 1.f)) >= TH;          // exact at boundary
    };

    // ---- phase 3: greedy via ballots ----
    float p1x = __shfl(cx, 0), p1y = __shfl(cy, 0), p1z = __shfl(cz, 0);
    unsigned long long ball1 =
        __ballot(my_pass(p1x, p1y, p1z)) & 0xFFFEull;   // ranks 1..15

    if (ball1 != 0) {                                   // wave-uniform
        const int i2 = __ffsll(ball1) - 1;
        float p2x = __shfl(cx, i2), p2y = __shfl(cy, i2), p2z = __shfl(cz, i2);
        unsigned long long ball3 =
            ball1 & __ballot(my_pass(p2x, p2y, p2z)) & ~((2ull << i2) - 1);
        if (ball3 != 0) {
            const int i3 = __ffsll(ball3) - 1;
            float p3x = __shfl(cx, i3), p3y = __shfl(cy, i3), p3z = __shfl(cz, i3);
            if (lane == 0) {
                float* ob = out + (size_t)b * 9;
                ob[0] = p1x; ob[1] = p1y; ob[2] = p1z;
                ob[3] = p2x; ob[4] = p2y; ob[5] = p2z;
                ob[6] = p3x; ob[7] = p3y; ob[8] = p3z;
            }
            return;
        }
    }

    // ---- rare fallback: full R6 masked-argmax over all 512 ----
    {
        // rebuild keys (reload conf: keeps c0/c1 dead on the hot path)
        float4 d0 = cb4[lane * 2 + 0];
        float4 d1 = cb4[lane * 2 + 1];
        {
            float f[8] = {d0.x, d0.y, d0.z, d0.w, d1.x, d1.y, d1.z, d1.w};
            #pragma unroll
            for (int s = 0; s < 8; ++s) {
                int bi = __float_as_int(f[s]);
                k[s] = (unsigned)bi ^ ((unsigned)(bi >> 31) | 0x80000000u);
            }
        }
        const float4* pb4 = reinterpret_cast<const float4*>(pb);
        float4 q0 = pb4[lane * 6 + 0];
        float4 q1 = pb4[lane * 6 + 1];
        float4 q2 = pb4[lane * 6 + 2];
        float4 q3 = pb4[lane * 6 + 3];
        float4 q4 = pb4[lane * 6 + 4];
        float4 q5 = pb4[lane * 6 + 5];
        float rx[8], ry[8], rz[8];
        rx[0] = q0.x; ry[0] = q0.y; rz[0] = q0.z;
        rx[1] = q0.w; ry[1] = q1.x; rz[1] = q1.y;
        rx[2] = q1.z; ry[2] = q1.w; rz[2] = q2.x;
        rx[3] = q2.y; ry[3] = q2.z; rz[3] = q2.w;
        rx[4] = q3.x; ry[4] = q3.y; rz[4] = q3.z;
        rx[5] = q3.w; ry[5] = q4.x; rz[5] = q4.y;
        rx[6] = q4.z; ry[6] = q4.w; rz[6] = q5.x;
        rx[7] = q5.y; ry[7] = q5.z; rz[7] = q5.w;

        auto argmax_idx = [&](unsigned& gm_out) -> int {
            unsigned m = k[0];
            #pragma unroll
            for (int s = 1; s < 8; ++s) m = k[s] > m ? k[s] : m;
            unsigned gm = m;
            #pragma unroll
            for (int off = 1; off < 64; off <<= 1) {
                unsigned o = __shfl_xor(gm, off);
                gm = o > gm ? o : gm;
            }
            int sl = 8;
            #pragma unroll
            for (int s = 7; s >= 0; --s)
                if (k[s] == gm) sl = s;
            unsigned long long ball = __ballot(sl < 8);
            int owner = __ffsll(ball) - 1;
            int osl = __shfl(sl, owner);
            gm_out = gm;
            return owner * 8 + osl;
        };
        auto get_row = [&](int w, float& x, float& y, float& z) {
            const int ow = w >> 3, sl = w & 7;
            float tx = rx[0], ty = ry[0], tz = rz[0];
            #pragma unroll
            for (int s = 1; s < 8; ++s)
                if (sl == s) { tx = rx[s]; ty = ry[s]; tz = rz[s]; }
            x = __shfl(tx, ow); y = __shfl(ty, ow); z = __shfl(tz, ow);
        };
        auto mask_keys = [&](float px, float py, float pz) {
            #pragma unroll
            for (int s = 0; s < 8; ++s) {
                float d = fabsf(rx[s] * px + ry[s] * py + rz[s] * pz);
                bool pass;
                if (d <= CLO)      pass = true;
                else if (d >= CHI) pass = false;
                else               pass = (acosf(fminf(d, 1.f)) >= TH);
                if (!pass) k[s] = 0u;
            }
        };

        unsigned gm1;
        int w1 = argmax_idx(gm1);
        float f1x, f1y, f1z;
        get_row(w1, f1x, f1y, f1z);
        {
            const int osl = ((w1 >> 3) == lane) ? (w1 & 7) : 8;
            #pragma unroll
            for (int s = 0; s < 8; ++s)
                if (osl == s) k[s] = 0u;
        }

        mask_keys(f1x, f1y, f1z);
        unsigned gm2;
        int w2 = argmax_idx(gm2);

        float o2x, o2y, o2z, o3x, o3y, o3z;
        if (gm2 != 0u) {                       // wave-uniform
            get_row(w2, o2x, o2y, o2z);
            mask_keys(o2x, o2y, o2z);          // w2 self-fails (|dot|=1)
            unsigned gm3;
            int w3 = argmax_idx(gm3);
            if (gm3 != 0u) get_row(w3, o3x, o3y, o3z);
            else           get_row(0, o3x, o3y, o3z);   // fallback pos[0]
        } else {
            get_row(0, o2x, o2y, o2z);                  // fallback pos[0]
            o3x = o2x; o3y = o2y; o3z = o2z;
        }

        if (lane == 0) {
            float* ob = out + (size_t)b * 9;
            ob[0] = f1x; ob[1] = f1y; ob[2] = f1z;
            ob[3] = o2x; ob[4] = o2y; ob[5] = o2z;
            ob[6] = o3x; ob[7] = o3y; ob[8] = o3z;
        }
    }
}

extern "C" void kernel_launch(void* const* d_in, const int* in_sizes, int n_in,
                              void* d_out, int out_size, void* d_ws, size_t ws_size,
                              hipStream_t stream) {
    const float* pred_logits = (const float*)d_in[0]; // [B, NQ, 1]
    const float* pred_pos    = (const float*)d_in[1]; // [B, NQ, 3]
    float* out = (float*)d_out;                       // [B, NUM, 3]

    const int grid = B_TOTAL / 4;                     // 4 waves/block
    greedy_nms_kernel<<<grid, 256, 0, stream>>>(pred_logits, pred_pos, out);
}

// Round 10
// 26.943 us; speedup vs baseline: 1.2203x; 1.1969x over previous
//
#include <hip/hip_runtime.h>
#include <math.h>

#define B_TOTAL 16384
#define NQ 512
#define NUM 3

// One wave per batch, 4 waves/block. R6's masked-argmax algorithm
// (#1 = argmax conf; #2 = argmax among passers vs p1; #3 = passers vs p1&p2)
// with a request-optimal data path:
//  - pos read column-major (contiguous 1KB per float4 instruction, 96 line
//    requests/wave instead of ~384 with the old 96B-lane-stride gather),
//    staged to LDS; element ownership n = i*64+lane makes every LDS read
//    conflict-free (banks 3*lane mod 32, 3 invertible mod 32).
//  - conf read as 8 column-major dwords (same n-mapping).
//  - argmax: per-lane tree + packed-u64 (key<<32 | 511-n) 6-step butterfly,
//    exact stable min-index tie-break.
//  - get_row = wave-uniform LDS broadcast read (no shuffles).
__global__ __launch_bounds__(256) void greedy_nms_kernel(
    const float* __restrict__ conf,   // [B, NQ]
    const float* __restrict__ pos,    // [B, NQ, 3]
    float* __restrict__ out)          // [B, NUM, 3]
{
    __shared__ float lds[4 * NQ * 3];            // 24 KB: 6 KB per wave
    const int lane = threadIdx.x & 63;
    const int wv   = threadIdx.x >> 6;
    const int b    = (blockIdx.x << 2) | wv;     // grid*4 == B_TOTAL

    const float* cb = conf + (size_t)b * NQ;
    const float* pb = pos  + (size_t)b * NQ * 3;
    float* wl = lds + wv * (NQ * 3);

    // ---- pos: column-major float4 loads (fully coalesced), stage to LDS ----
    const float4* pb4 = reinterpret_cast<const float4*>(pb);
    float4 t0 = pb4[0 * 64 + lane];
    float4 t1 = pb4[1 * 64 + lane];
    float4 t2 = pb4[2 * 64 + lane];
    float4 t3 = pb4[3 * 64 + lane];
    float4 t4 = pb4[4 * 64 + lane];
    float4 t5 = pb4[5 * 64 + lane];

    // ---- conf: column-major dwords; slot i <-> element n = i*64+lane ----
    float c[8];
    #pragma unroll
    for (int i = 0; i < 8; ++i) c[i] = cb[i * 64 + lane];

    float4* wl4 = reinterpret_cast<float4*>(wl);
    wl4[0 * 64 + lane] = t0;
    wl4[1 * 64 + lane] = t1;
    wl4[2 * 64 + lane] = t2;
    wl4[3 * 64 + lane] = t3;
    wl4[4 * 64 + lane] = t4;
    wl4[5 * 64 + lane] = t5;

    // monotone float->u32 keys; key 0 == consumed/failed (no NaN/-inf input)
    unsigned k[8];
    #pragma unroll
    for (int i = 0; i < 8; ++i) {
        int bi = __float_as_int(c[i]);
        k[i] = (unsigned)bi ^ ((unsigned)(bi >> 31) | 0x80000000u);
    }

    __syncthreads();

    // exact argmax -> packed u64 (hi = key, lo = 511-n); tie -> larger lo
    // -> smaller n, identical to stable argsort(-conf).
    auto argmax64 = [&]() -> unsigned long long {
        unsigned m = k[0]; int im = 0;
        #pragma unroll
        for (int i = 1; i < 8; ++i)
            if (k[i] > m) { m = k[i]; im = i; }   // keeps smallest i on tie
        unsigned long long key =
            ((unsigned long long)m << 32) |
            (unsigned)(NQ - 1 - (im * 64 + lane));
        #pragma unroll
        for (int off = 1; off < 64; off <<= 1) {
            unsigned long long o = __shfl_xor(key, off);
            if (o > key) key = o;
        }
        return key;
    };

    // wave-uniform n -> broadcast LDS read (no bank conflicts: same addr)
    auto get_row = [&](int n, float& x, float& y, float& z) {
        x = wl[3 * n + 0]; y = wl[3 * n + 1]; z = wl[3 * n + 2];
    };

    const float TH  = 0.78539816339744830961f; // pi/4 (f32 == jnp thresh)
    const float CLO = 0.70710478f;             // cos(pi/4) - ~2e-6
    const float CHI = 0.70710878f;             // cos(pi/4) + ~2e-6

    // zero keys of items failing the angle test vs (px,py,pz); reads are
    // conflict-free: dword index 192i+3*lane -> bank 3*lane mod 32.
    auto mask_keys = [&](float px, float py, float pz) {
        #pragma unroll
        for (int i = 0; i < 8; ++i) {
            const int o = 3 * (i * 64 + lane);
            float x = wl[o + 0], y = wl[o + 1], z = wl[o + 2];
            float d = fabsf(x * px + y * py + z * pz);
            bool pass;
            if (d <= CLO)      pass = true;   // clearly >= pi/4
            else if (d >= CHI) pass = false;  // clearly <  pi/4
            else               pass = (acosf(fminf(d, 1.f)) >= TH); // exact
            if (!pass) k[i] = 0u;
        }
    };

    // ---- #1: global argmax ----
    unsigned long long K1 = argmax64();
    const int w1 = NQ - 1 - (int)(K1 & 0x1ffu);
    float p1x, p1y, p1z;
    get_row(w1, p1x, p1y, p1z);
    {   // consume w1
        const int ci = ((w1 & 63) == lane) ? (w1 >> 6) : 8;
        #pragma unroll
        for (int i = 0; i < 8; ++i)
            if (ci == i) k[i] = 0u;
    }

    // ---- #2: argmax among items passing vs p1 ----
    mask_keys(p1x, p1y, p1z);
    unsigned long long K2 = argmax64();

    float o2x, o2y, o2z, o3x, o3y, o3z;
    if ((unsigned)(K2 >> 32) != 0u) {          // wave-uniform
        const int w2 = NQ - 1 - (int)(K2 & 0x1ffu);
        get_row(w2, o2x, o2y, o2z);
        // ---- #3: additionally pass vs p2 (w2 self-fails: |dot|=1) ----
        mask_keys(o2x, o2y, o2z);
        unsigned long long K3 = argmax64();
        if ((unsigned)(K3 >> 32) != 0u) {
            const int w3 = NQ - 1 - (int)(K3 & 0x1ffu);
            get_row(w3, o3x, o3y, o3z);
        } else {
            get_row(0, o3x, o3y, o3z);         // fallback = pos[0]
        }
    } else {
        get_row(0, o2x, o2y, o2z);             // fallback = pos[0]
        o3x = o2x; o3y = o2y; o3z = o2z;
    }

    if (lane == 0) {
        float* ob = out + (size_t)b * 9;
        ob[0] = p1x; ob[1] = p1y; ob[2] = p1z;
        ob[3] = o2x; ob[4] = o2y; ob[5] = o2z;
        ob[6] = o3x; ob[7] = o3y; ob[8] = o3z;
    }
}

extern "C" void kernel_launch(void* const* d_in, const int* in_sizes, int n_in,
                              void* d_out, int out_size, void* d_ws, size_t ws_size,
                              hipStream_t stream) {
    const float* pred_logits = (const float*)d_in[0]; // [B, NQ, 1]
    const float* pred_pos    = (const float*)d_in[1]; // [B, NQ, 3]
    float* out = (float*)d_out;                       // [B, NUM, 3]

    const int grid = B_TOTAL / 4;                     // 4 waves/block
    greedy_nms_kernel<<<grid, 256, 0, stream>>>(pred_logits, pred_pos, out);
}